// Round 11
// baseline (68.707 us; speedup 1.0000x reference)
//
#include <hip/hip_runtime.h>

// 5-level wavedec (filter len 8, pywt 'symmetric'), 4096 rows of 8192 f32.
// Lengths: 8192 -> 4099 -> 2053 -> 1030 -> 518 -> 262
// Out: approx(262) @0, d5(262), d4(518), d3(1030), d2(2053), d1(4099).
//
// R11 = R8 fusion, seam-poison fixed. L1+L2 fused through registers+shuffles;
// the 96 wave-seam a1 values are precomputed ONCE into a small LDS table
// (parallel, direct loads) instead of R8's per-iteration 48-load recompute
// under exec mask (that was R8's entire regression). a1 never touches LDS.
// LDS = seam(96) + a2(2056) + a3(1032) = 12.8 KB -> 8 blocks/CU.

static constexpr int ROWS = 4096;
static constexpr int N0 = 8192;
static constexpr int L1n = 4099, L2n = 2053, L3n = 1030, L4n = 518, L5n = 262;
static constexpr size_t OFF_D5 = 1073152u;
static constexpr size_t OFF_D4 = 2146304u;
static constexpr size_t OFF_D3 = 4268032u;
static constexpr size_t OFF_D2 = 8486912u;
static constexpr size_t OFF_D1 = 16896000u;

__device__ __forceinline__ float refl_load(const float* __restrict__ s, int idx, int n) {
    int i = (idx < 0) ? (-1 - idx) : ((idx >= n) ? (2 * n - 1 - idx) : idx);
    return s[i];
}

// a1[i] honestly from x (with x-reflection), 8 FMA
__device__ __forceinline__ float a1_val(const float* __restrict__ xr, int i,
                                        const float* __restrict__ h) {
    float a = 0.f;
#pragma unroll
    for (int q = 0; q < 8; ++q)
        a = fmaf(h[q], refl_load(xr, 2 * i + 1 - q, N0), a);
    return a;
}

// a1[i] for interior i (all x indices in-bounds): 8 direct loads
__device__ __forceinline__ float a1_val_int(const float* __restrict__ xr, int i,
                                            const float* __restrict__ h) {
    float a = 0.f;
#pragma unroll
    for (int q = 0; q < 8; ++q)
        a = fmaf(h[q], xr[2 * i + 1 - q], a);
    return a;
}

// R3-proven generic level for L3/L4/L5 (LDS src, 4 outputs/thread)
__device__ __forceinline__ void dwt_level(
    const float* __restrict__ src, int n, int m,
    const float* __restrict__ h, const float* __restrict__ g,
    float* __restrict__ adst, float* __restrict__ ddst, int tid)
{
    const int ngroups = (m + 3) >> 2;
    const int jmax = (n - 10) >> 3;
    for (int j = tid; j < ngroups; j += 256) {
        const int p0 = 4 * j;
        if (j >= 1 && j <= jmax && p0 + 3 < m) {
            const float2* __restrict__ s2 =
                reinterpret_cast<const float2*>(src) + (4 * j - 3);
            float w[16];
#pragma unroll
            for (int t = 0; t < 8; ++t) {
                const float2 v = s2[t];
                w[2 * t] = v.x; w[2 * t + 1] = v.y;
            }
#pragma unroll
            for (int r = 0; r < 4; ++r) {
                float a = 0.f, d = 0.f;
#pragma unroll
                for (int q = 0; q < 8; ++q) {
                    const float v = w[2 * r + 7 - q];
                    a = fmaf(h[q], v, a);
                    d = fmaf(g[q], v, d);
                }
                ddst[p0 + r] = d;
                adst[p0 + r] = a;
            }
        } else {
#pragma unroll 4
            for (int r = 0; r < 4; ++r) {
                const int pos = p0 + r;
                if (pos >= m) break;
                const int s0 = 2 * pos + 1;
                float a = 0.f, d = 0.f;
#pragma unroll
                for (int q = 0; q < 8; ++q) {
                    const float v = refl_load(src, s0 - q, n);
                    a = fmaf(h[q], v, a);
                    d = fmaf(g[q], v, d);
                }
                ddst[pos] = d;
                adst[pos] = a;
            }
        }
    }
}

__global__ __launch_bounds__(256, 8)
void wavedec5_fused(const float* __restrict__ x,
                    const float* __restrict__ dlo,
                    const float* __restrict__ dhi,
                    float* __restrict__ out)
{
    __shared__ __align__(16) float seam[96];      // 16 seams x 6 a1 values
    __shared__ __align__(16) float a2buf[2056];   // a2 (2053), later a4 (518)
    __shared__ __align__(16) float a3buf[1032];   // a3 (1030)

    const int tid  = threadIdx.x;
    const int lane = tid & 63;
    const int row  = blockIdx.x;

    float h[8], g[8];
#pragma unroll
    for (int i = 0; i < 8; ++i) { h[i] = dlo[i]; g[i] = dhi[i]; }

    const float* __restrict__ xr = x + (size_t)row * N0;
    float* __restrict__ d1out = out + OFF_D1 + (size_t)row * L1n;
    float* __restrict__ d2out = out + OFF_D2 + (size_t)row * L2n;

    // ---- pre-phase: seam table + edges (disjoint tid ranges) ----
    if (tid < 96) {
        // seam s = iter*4 + wave; lane-0 group js = 3 + 256*iter + 64*wave
        const int s = tid / 6, o = tid % 6;
        const int js = 3 + 256 * (s >> 2) + 64 * (s & 3);
        seam[tid] = a1_val_int(xr, 4 * js - 6 + o, h);   // all interior
    } else if (tid < 109) {
        // a2/d2 edge positions {0..5, 2046..2052} (honest, reflected)
        const int t = tid - 96;
        const int p = (t < 6) ? t : (2040 + t);
        float a2v = 0.f, d2v = 0.f;
#pragma unroll
        for (int q = 0; q < 8; ++q) {
            int s = 2 * p + 1 - q;
            int si = (s < 0) ? (-1 - s) : ((s >= L1n) ? (2 * L1n - 1 - s) : s);
            const float av = a1_val(xr, si, h);
            a2v = fmaf(h[q], av, a2v);
            d2v = fmaf(g[q], av, d2v);
        }
        a2buf[p] = a2v;
        d2out[p] = d2v;
    } else if (tid < 114) {
        // d1 edge groups {0,1,2,1023,1024} (d1[0..11], d1[4092..4098])
        const int t = tid - 109;
        const int j = (t == 3) ? 1023 : ((t == 4) ? 1024 : t);
#pragma unroll 4
        for (int r = 0; r < 4; ++r) {
            const int pos = 4 * j + r;
            if (pos >= L1n) break;
            const int s0 = 2 * pos + 1;
            float d = 0.f;
#pragma unroll
            for (int q = 0; q < 8; ++q)
                d = fmaf(g[q], refl_load(xr, s0 - q, N0), d);
            d1out[pos] = d;
        }
    }
    __syncthreads();   // seam table (and edge a2) visible

    // ---- fused L1+L2 main loop: j in [3,1022], 4 rounds ----
    for (int iter = 0, j = 3 + tid; j <= 1022; ++iter, j += 256) {
        // 16-float x window [8j-6 .. 8j+9] (interior)
        const float2* __restrict__ s2 =
            reinterpret_cast<const float2*>(xr) + (4 * j - 3);
        float w[16];
#pragma unroll
        for (int t = 0; t < 8; ++t) {
            const float2 v = s2[t];
            w[2 * t] = v.x; w[2 * t + 1] = v.y;
        }
        float a1o[4], dd[4];
#pragma unroll
        for (int r = 0; r < 4; ++r) {
            float a = 0.f, d = 0.f;
#pragma unroll
            for (int q = 0; q < 8; ++q) {
                const float v = w[2 * r + 7 - q];   // x[2(4j+r)+1-q]
                a = fmaf(h[q], v, a);
                d = fmaf(g[q], v, d);
            }
            a1o[r] = a; dd[r] = d;
        }
#pragma unroll
        for (int r = 0; r < 4; ++r) d1out[4 * j + r] = dd[r];

        // a1[4j-6 .. 4j-1] from lanes l-1/l-2; lanes 0,1 patch from seam LDS
        float v0 = __shfl_up(a1o[2], 2, 64);   // a1[4j-6]
        float v1 = __shfl_up(a1o[3], 2, 64);   // a1[4j-5]
        float v2 = __shfl_up(a1o[0], 1, 64);   // a1[4j-4]
        float v3 = __shfl_up(a1o[1], 1, 64);   // a1[4j-3]
        float v4 = __shfl_up(a1o[2], 1, 64);   // a1[4j-2]
        float v5 = __shfl_up(a1o[3], 1, 64);   // a1[4j-1]
        const int sb = (iter * 4 + (tid >> 6)) * 6;
        if (lane == 0) {
            v0 = seam[sb];     v1 = seam[sb + 1];
            v2 = seam[sb + 2]; v3 = seam[sb + 3];
            v4 = seam[sb + 4]; v5 = seam[sb + 5];
        } else if (lane == 1) {
            v0 = seam[sb + 4]; v1 = seam[sb + 5];
        }
        float v[10] = {v0, v1, v2, v3, v4, v5, a1o[0], a1o[1], a1o[2], a1o[3]};
        // a2[p]=sum h[q]*a1[2p+1-q]: p=2j -> v[7-q]; p=2j+1 -> v[9-q]
        float a20 = 0.f, d20 = 0.f, a21 = 0.f, d21 = 0.f;
#pragma unroll
        for (int q = 0; q < 8; ++q) {
            a20 = fmaf(h[q], v[7 - q], a20);
            d20 = fmaf(g[q], v[7 - q], d20);
            a21 = fmaf(h[q], v[9 - q], a21);
            d21 = fmaf(g[q], v[9 - q], d21);
        }
        a2buf[2 * j]     = a20;
        a2buf[2 * j + 1] = a21;
        d2out[2 * j]     = d20;
        d2out[2 * j + 1] = d21;
    }
    __syncthreads();

    // L3: a2buf -> a3buf, d3 -> global
    dwt_level(a2buf, L2n, L3n, h, g, a3buf,
              out + OFF_D3 + (size_t)row * L3n, tid);
    __syncthreads();
    // L4: a3buf -> a2buf (a2 dead), d4 -> global
    dwt_level(a3buf, L3n, L4n, h, g, a2buf,
              out + OFF_D4 + (size_t)row * L4n, tid);
    __syncthreads();
    // L5: a2buf(a4) -> approx & d5 straight to global
    dwt_level(a2buf, L4n, L5n, h, g,
              out + (size_t)row * L5n,
              out + OFF_D5 + (size_t)row * L5n, tid);
}

extern "C" void kernel_launch(void* const* d_in, const int* in_sizes, int n_in,
                              void* d_out, int out_size, void* d_ws, size_t ws_size,
                              hipStream_t stream) {
    const float* x   = (const float*)d_in[0];
    const float* dlo = (const float*)d_in[1];
    const float* dhi = (const float*)d_in[2];
    float* out = (float*)d_out;
    wavedec5_fused<<<ROWS, 256, 0, stream>>>(x, dlo, dhi, out);
}

// Round 12
// 62.420 us; speedup vs baseline: 1.1007x; 1.1007x over previous
//
#include <hip/hip_runtime.h>

// 5-level wavedec (filter len 8, pywt 'symmetric'), 4096 rows of 8192 f32.
// Lengths: 8192 -> 4099 -> 2053 -> 1030 -> 518 -> 262
// Out: approx(262) @0, d5(262), d4(518), d3(1030), d2(2053), d1(4099).
//
// R12 = R3 structure + ILP=2: each loop body processes TWO independent
// groups (j and j+H, opposite halves of the level). Both 16-float windows
// are loaded back-to-back before either compute -> two memory chains in
// flight per thread (the compiler never achieved this across iterations:
// VGPR stayed 40 in R3/R9/R10). Also halves rounds/level (12 -> 8).

static constexpr int ROWS = 4096;
static constexpr int N0 = 8192;
static constexpr int L1n = 4099, L2n = 2053, L3n = 1030, L4n = 518, L5n = 262;
static constexpr size_t OFF_D5 = 1073152u;
static constexpr size_t OFF_D4 = 2146304u;
static constexpr size_t OFF_D3 = 4268032u;
static constexpr size_t OFF_D2 = 8486912u;
static constexpr size_t OFF_D1 = 16896000u;

__device__ __forceinline__ float refl_load(const float* __restrict__ s, int idx, int n) {
    int i = (idx < 0) ? (-1 - idx) : ((idx >= n) ? (2 * n - 1 - idx) : idx);
    return s[i];
}

// w[0..15] = src[8j-6 .. 8j+9] (interior groups only)
__device__ __forceinline__ void load_win(const float* __restrict__ src, int j,
                                         float* __restrict__ w) {
    const float2* __restrict__ s2 = reinterpret_cast<const float2*>(src) + (4 * j - 3);
#pragma unroll
    for (int t = 0; t < 8; ++t) {
        const float2 v = s2[t];
        w[2 * t] = v.x; w[2 * t + 1] = v.y;
    }
}

__device__ __forceinline__ void compute_store(
    const float* __restrict__ w,
    const float* __restrict__ h, const float* __restrict__ g,
    float* __restrict__ adst, float* __restrict__ ddst, int p0)
{
    float aa[4], dd[4];
#pragma unroll
    for (int r = 0; r < 4; ++r) {
        float a = 0.f, d = 0.f;
#pragma unroll
        for (int q = 0; q < 8; ++q) {
            const float v = w[2 * r + 7 - q];   // src[2(p0+r)+1-q]
            a = fmaf(h[q], v, a);
            d = fmaf(g[q], v, d);
        }
        aa[r] = a; dd[r] = d;
    }
#pragma unroll
    for (int r = 0; r < 4; ++r) ddst[p0 + r] = dd[r];
#pragma unroll
    for (int r = 0; r < 4; ++r) adst[p0 + r] = aa[r];
}

__device__ __forceinline__ void edge_group(
    const float* __restrict__ src, int n, int m,
    const float* __restrict__ h, const float* __restrict__ g,
    float* __restrict__ adst, float* __restrict__ ddst, int j)
{
#pragma unroll 4
    for (int r = 0; r < 4; ++r) {
        const int pos = 4 * j + r;
        if (pos >= m) break;
        const int s0 = 2 * pos + 1;
        float a = 0.f, d = 0.f;
#pragma unroll
        for (int q = 0; q < 8; ++q) {
            const float v = refl_load(src, s0 - q, n);
            a = fmaf(h[q], v, a);
            d = fmaf(g[q], v, d);
        }
        ddst[pos] = d;
        adst[pos] = a;
    }
}

// One DWT level with ILP=2: body handles groups j and j+H (independent).
__device__ __forceinline__ void dwt_level(
    const float* __restrict__ src, int n, int m,
    const float* __restrict__ h, const float* __restrict__ g,
    float* __restrict__ adst, float* __restrict__ ddst, int tid)
{
    const int G = (m + 3) >> 2;        // total groups
    const int H = (G + 1) >> 1;        // half (first index range)
    const int jmax = (n - 10) >> 3;    // interior iff 1 <= j <= jmax

    for (int j = tid; j < H; j += 256) {
        const int j2 = j + H;
        const bool v2 = (j2 < G);
        const bool i1 = (j >= 1) && (j <= jmax) && (4 * j + 3 < m);
        const bool i2 = v2 && (j2 <= jmax) && (4 * j2 + 3 < m);

        float w1[16], w2[16];
        if (i1) load_win(src, j,  w1);   // two independent windows
        if (i2) load_win(src, j2, w2);   // issued before any compute

        if (i1) compute_store(w1, h, g, adst, ddst, 4 * j);
        else    edge_group(src, n, m, h, g, adst, ddst, j);

        if (i2)      compute_store(w2, h, g, adst, ddst, 4 * j2);
        else if (v2) edge_group(src, n, m, h, g, adst, ddst, j2);
    }
}

__global__ __launch_bounds__(256, 4)
void wavedec5_kernel(const float* __restrict__ x,
                     const float* __restrict__ dlo,
                     const float* __restrict__ dhi,
                     float* __restrict__ out)
{
    __shared__ __align__(16) float bufA[4100];  // a1 / a3
    __shared__ __align__(16) float bufB[2056];  // a2 / a4

    const int row = blockIdx.x;
    const int tid = threadIdx.x;

    float h[8], g[8];
#pragma unroll
    for (int i = 0; i < 8; ++i) { h[i] = dlo[i]; g[i] = dhi[i]; }

    const float* __restrict__ xr = x + (size_t)row * N0;

    // L1: global -> bufA, d1 -> global
    dwt_level(xr, N0, L1n, h, g, bufA,
              out + OFF_D1 + (size_t)row * L1n, tid);
    __syncthreads();
    // L2: bufA -> bufB, d2 -> global
    dwt_level(bufA, L1n, L2n, h, g, bufB,
              out + OFF_D2 + (size_t)row * L2n, tid);
    __syncthreads();
    // L3: bufB -> bufA, d3 -> global
    dwt_level(bufB, L2n, L3n, h, g, bufA,
              out + OFF_D3 + (size_t)row * L3n, tid);
    __syncthreads();
    // L4: bufA -> bufB, d4 -> global
    dwt_level(bufA, L3n, L4n, h, g, bufB,
              out + OFF_D4 + (size_t)row * L4n, tid);
    __syncthreads();
    // L5: bufB -> approx & d5 straight to global
    dwt_level(bufB, L4n, L5n, h, g,
              out + (size_t)row * L5n,
              out + OFF_D5 + (size_t)row * L5n, tid);
}

extern "C" void kernel_launch(void* const* d_in, const int* in_sizes, int n_in,
                              void* d_out, int out_size, void* d_ws, size_t ws_size,
                              hipStream_t stream) {
    const float* x   = (const float*)d_in[0];
    const float* dlo = (const float*)d_in[1];
    const float* dhi = (const float*)d_in[2];
    float* out = (float*)d_out;
    wavedec5_kernel<<<ROWS, 256, 0, stream>>>(x, dlo, dhi, out);
}